// Round 1
// baseline (1327.563 us; speedup 1.0000x reference)
//
#include <hip/hip_runtime.h>

#define NN 20000
#define NE 160000
#define NEF 180000  // edges + self loops

// ---------- ordered-float encoding for atomicMax on possibly-negative floats ----
static __device__ __forceinline__ unsigned enc_f(float f) {
  unsigned u = __float_as_uint(f);
  return (u & 0x80000000u) ? ~u : (u | 0x80000000u);
}
static __device__ __forceinline__ float dec_f(unsigned e) {
  return (e & 0x80000000u) ? __uint_as_float(e & 0x7fffffffu) : __uint_as_float(~e);
}

// ---------- generic f32 GEMM: C[M,N] = A[M,K] @ B[K,N] (+bias) ----------
// 64x64 tile, BK=16, 256 threads, 4x4 per thread.
__global__ __launch_bounds__(256) void gemm_k(
    const float* __restrict__ A, const float* __restrict__ B,
    const float* __restrict__ bias, float* __restrict__ C,
    int M, int N, int K)
{
  __shared__ float As[16][65];
  __shared__ float Bs[16][65];
  const int bn = blockIdx.x * 64;
  const int bm = blockIdx.y * 64;
  const int tid = threadIdx.x;
  const int tx = tid & 15;   // n group
  const int ty = tid >> 4;   // m group
  float acc[4][4] = {{0.f}};
  for (int k0 = 0; k0 < K; k0 += 16) {
    #pragma unroll
    for (int i = 0; i < 4; i++) {       // A tile: 64 m x 16 k, k fastest (coalesced 16-wide)
      int idx = tid + i * 256;
      int m = idx >> 4, k = idx & 15;
      int gm = bm + m;
      As[k][m] = (gm < M) ? A[(long long)gm * K + (k0 + k)] : 0.f;
    }
    #pragma unroll
    for (int i = 0; i < 4; i++) {       // B tile: 16 k x 64 n, n fastest (coalesced 64-wide)
      int idx = tid + i * 256;
      int k = idx >> 6, n = idx & 63;
      int gn = bn + n;
      Bs[k][n] = (gn < N) ? B[(long long)(k0 + k) * N + gn] : 0.f;
    }
    __syncthreads();
    #pragma unroll
    for (int k = 0; k < 16; k++) {
      float a[4], b[4];
      #pragma unroll
      for (int i = 0; i < 4; i++) a[i] = As[k][ty * 4 + i];
      #pragma unroll
      for (int j = 0; j < 4; j++) b[j] = Bs[k][tx * 4 + j];
      #pragma unroll
      for (int i = 0; i < 4; i++)
        #pragma unroll
        for (int j = 0; j < 4; j++)
          acc[i][j] = fmaf(a[i], b[j], acc[i][j]);
    }
    __syncthreads();
  }
  #pragma unroll
  for (int i = 0; i < 4; i++) {
    int gm = bm + ty * 4 + i;
    if (gm >= M) continue;
    #pragma unroll
    for (int j = 0; j < 4; j++) {
      int gn = bn + tx * 4 + j;
      if (gn >= N) continue;
      float v = acc[i][j];
      if (bias) v += bias[gn];
      C[(long long)gm * N + gn] = v;
    }
  }
}

// ---------- edge kernels ----------
__global__ void k_count(const int* __restrict__ dst, float* __restrict__ cnt) {
  int e = blockIdx.x * 256 + threadIdx.x;
  if (e < NE) atomicAdd(&cnt[dst[e]], 1.0f);
}

template<int LOGC>
__global__ void k_gather(const int* __restrict__ src, const int* __restrict__ dst,
                         const float* __restrict__ feat, float* __restrict__ acc) {
  long long t = (long long)blockIdx.x * 256 + threadIdx.x;
  if (t >= ((long long)NE << LOGC)) return;
  int e = (int)(t >> LOGC);
  int c = (int)(t & ((1 << LOGC) - 1));
  atomicAdd(&acc[((long long)dst[e] << LOGC) + c], feat[((long long)src[e] << LOGC) + c]);
}

template<int LOGC, bool ADD_RES>
__global__ void k_sage_combine(const float* __restrict__ agg, const float* __restrict__ cnt,
                               const float* __restrict__ linr, const float* __restrict__ resx,
                               float* __restrict__ out) {
  long long t = (long long)blockIdx.x * 256 + threadIdx.x;
  if (t >= ((long long)NN << LOGC)) return;
  int i = (int)(t >> LOGC);
  float v = agg[t] / fmaxf(cnt[i], 1.f) + linr[t];
  v = fmaxf(v, 0.f);
  if (ADD_RES) v += resx[t];
  out[t] = v;
}

// one 64-lane wave per (node, head): dot(hg_row, att_src/att_dst)
__global__ void k_gat_scores(const float* __restrict__ hg, const float* __restrict__ att_s,
                             const float* __restrict__ att_d, float* __restrict__ a_s,
                             float* __restrict__ a_d) {
  int gtid = blockIdx.x * 256 + threadIdx.x;
  int row = gtid >> 6;          // i*8 + h
  int lane = threadIdx.x & 63;
  if (row >= NN * 8) return;
  int h = row & 7;
  const float* r = hg + (long long)row * 128;
  float v0 = r[lane], v1 = r[lane + 64];
  float s = v0 * att_s[h * 128 + lane] + v1 * att_s[h * 128 + lane + 64];
  float d = v0 * att_d[h * 128 + lane] + v1 * att_d[h * 128 + lane + 64];
  #pragma unroll
  for (int o = 32; o > 0; o >>= 1) { s += __shfl_down(s, o); d += __shfl_down(d, o); }
  if (lane == 0) { a_s[row] = s; a_d[row] = d; }
}

__global__ void k_minit(unsigned* __restrict__ m) {
  int t = blockIdx.x * 256 + threadIdx.x;
  if (t < NN * 8) m[t] = enc_f(-3.0e38f);
}

static __device__ __forceinline__ void ef_sd(int ef, const int* src, const int* dst, int& s, int& d) {
  if (ef < NE) { s = src[ef]; d = dst[ef]; } else { s = d = ef - NE; }
}

__global__ void k_gat_max(const int* __restrict__ src, const int* __restrict__ dst,
                          const float* __restrict__ a_s, const float* __restrict__ a_d,
                          unsigned* __restrict__ m) {
  int t = blockIdx.x * 256 + threadIdx.x;
  if (t >= NEF * 8) return;
  int ef = t >> 3, h = t & 7;
  int s, d; ef_sd(ef, src, dst, s, d);
  float e = a_s[s * 8 + h] + a_d[d * 8 + h];
  e = (e > 0.f) ? e : 0.2f * e;
  atomicMax(&m[d * 8 + h], enc_f(e));
}

__global__ void k_gat_exp(const int* __restrict__ src, const int* __restrict__ dst,
                          const float* __restrict__ a_s, const float* __restrict__ a_d,
                          const unsigned* __restrict__ m, float* __restrict__ ee,
                          float* __restrict__ denom) {
  int t = blockIdx.x * 256 + threadIdx.x;
  if (t >= NEF * 8) return;
  int ef = t >> 3, h = t & 7;
  int s, d; ef_sd(ef, src, dst, s, d);
  float e = a_s[s * 8 + h] + a_d[d * 8 + h];
  e = (e > 0.f) ? e : 0.2f * e;
  float v = expf(e - dec_f(m[d * 8 + h]));
  ee[t] = v;
  atomicAdd(&denom[d * 8 + h], v);
}

__global__ void k_gat_alpha(const int* __restrict__ dst, float* __restrict__ ee,
                            const float* __restrict__ denom) {
  int t = blockIdx.x * 256 + threadIdx.x;
  if (t >= NEF * 8) return;
  int ef = t >> 3, h = t & 7;
  int d = (ef < NE) ? dst[ef] : ef - NE;
  ee[t] /= denom[d * 8 + h];
}

__global__ void k_gat_agg(const int* __restrict__ src, const int* __restrict__ dst,
                          const float* __restrict__ ee, const float* __restrict__ hg,
                          float* __restrict__ gat) {
  long long t = (long long)blockIdx.x * 256 + threadIdx.x;
  if (t >= (long long)NEF * 1024) return;
  int ef = (int)(t >> 10);
  int k = (int)(t & 1023);
  int h = k >> 7;
  int s, d; ef_sd(ef, src, dst, s, d);
  float a = ee[ef * 8 + h];
  atomicAdd(&gat[((long long)d << 10) + k], a * hg[((long long)s << 10) + k]);
}

__global__ void k_bias_relu(float* __restrict__ g, const float* __restrict__ b) {
  long long t = (long long)blockIdx.x * 256 + threadIdx.x;
  if (t >= (long long)NN * 1024) return;
  g[t] = fmaxf(g[t] + b[t & 1023], 0.f);
}

__global__ void k_dinv(const float* __restrict__ cnt, float* __restrict__ dinv) {
  int i = blockIdx.x * 256 + threadIdx.x;
  if (i < NN) dinv[i] = rsqrtf(cnt[i] + 1.0f);   // deg includes self-loop
}

template<int LOGC>
__global__ void k_gcn_agg(const int* __restrict__ src, const int* __restrict__ dst,
                          const float* __restrict__ dinv, const float* __restrict__ hw,
                          float* __restrict__ acc) {
  long long t = (long long)blockIdx.x * 256 + threadIdx.x;
  if (t >= ((long long)NEF << LOGC)) return;
  int ef = (int)(t >> LOGC);
  int c = (int)(t & ((1 << LOGC) - 1));
  int s, d; ef_sd(ef, src, dst, s, d);
  float nrm = dinv[s] * dinv[d];
  atomicAdd(&acc[((long long)d << LOGC) + c], nrm * hw[((long long)s << LOGC) + c]);
}

template<int LOGC>
__global__ void k_add_bias(float* __restrict__ a, const float* __restrict__ b) {
  long long t = (long long)blockIdx.x * 256 + threadIdx.x;
  if (t >= ((long long)NN << LOGC)) return;
  a[t] += b[t & ((1 << LOGC) - 1)];
}

__global__ void k_logsoftmax(const float* __restrict__ acc, const float* __restrict__ bias,
                             float* __restrict__ out) {
  int i = blockIdx.x * 256 + threadIdx.x;
  if (i >= NN) return;
  float v[32]; float mx = -3e38f;
  #pragma unroll
  for (int c = 0; c < 32; c++) { v[c] = acc[i * 32 + c] + bias[c]; mx = fmaxf(mx, v[c]); }
  float s = 0.f;
  #pragma unroll
  for (int c = 0; c < 32; c++) s += expf(v[c] - mx);
  float ls = logf(s) + mx;
  #pragma unroll
  for (int c = 0; c < 32; c++) out[i * 32 + c] = v[c] - ls;
}

extern "C" void kernel_launch(void* const* d_in, const int* in_sizes, int n_in,
                              void* d_out, int out_size, void* d_ws, size_t ws_size,
                              hipStream_t stream) {
  const float* x     = (const float*)d_in[0];
  const int*   ei    = (const int*)d_in[1];
  const float* W_l1  = (const float*)d_in[2];
  const float* b_l1  = (const float*)d_in[3];
  const float* W_r1  = (const float*)d_in[4];
  const float* W_l2  = (const float*)d_in[5];
  const float* b_l2  = (const float*)d_in[6];
  const float* W_r2  = (const float*)d_in[7];
  const float* W_g   = (const float*)d_in[8];
  const float* att_s = (const float*)d_in[9];
  const float* att_d = (const float*)d_in[10];
  const float* b_g   = (const float*)d_in[11];
  const float* W_c1  = (const float*)d_in[12];
  const float* b_c1  = (const float*)d_in[13];
  const float* W_c2  = (const float*)d_in[14];
  const float* b_c2  = (const float*)d_in[15];
  const float* W_res = (const float*)d_in[16];
  const float* b_res = (const float*)d_in[17];
  const int* src = ei;
  const int* dst = ei + NE;
  float* out = (float*)d_out;

  // ---- workspace layout (floats) ----
  float* Wf = (float*)d_ws;
  size_t off = 0;
  auto take = [&](size_t n) { float* p = Wf + off; off += n; return p; };
  float* BIG0  = take((size_t)NN * 1024);   // hosts xw1/xr1/agg1 -> hw2/hr2/agg2 -> hg
  float* BIG1  = take((size_t)NN * 1024);   // hosts resx/h1/h2 -> gat accumulator (=h3)
  float* cnt   = take(NN);
  float* dinv  = take(NN);
  float* a_s   = take((size_t)NN * 8);
  float* a_d   = take((size_t)NN * 8);
  unsigned* menc = (unsigned*)take((size_t)NN * 8);
  float* denom = take((size_t)NN * 8);
  float* ee    = take((size_t)NEF * 8);
  float* hw64  = take((size_t)NN * 64);
  float* acc64 = take((size_t)NN * 64);
  float* hw32  = take((size_t)NN * 32);
  float* acc32 = take((size_t)NN * 32);
  (void)ws_size; (void)in_sizes; (void)n_in; (void)out_size;

  float* xw1  = BIG0;
  float* xr1  = BIG0 + (size_t)NN * 64;
  float* agg1 = BIG0 + (size_t)NN * 128;
  float* hw2  = BIG0;
  float* hr2  = BIG0 + (size_t)NN * 128;
  float* agg2 = BIG0 + (size_t)NN * 256;
  float* hg   = BIG0;
  float* resx = BIG1;
  float* h1   = BIG1 + (size_t)NN * 64;
  float* h2   = BIG1 + (size_t)NN * 128;
  float* gat  = BIG1;

  auto nb = [](long long t) { return dim3((unsigned)((t + 255) / 256)); };
  const unsigned MB = (NN + 63) / 64;   // 313 M-tiles

  // in-degree counts (original edges)
  hipMemsetAsync(cnt, 0, NN * sizeof(float), stream);
  k_count<<<nb(NE), 256, 0, stream>>>(dst, cnt);

  // ---- SAGE1 + residual ----
  gemm_k<<<dim3(1, MB), 256, 0, stream>>>(x, W_res, b_res, resx, NN, 64, 256);
  gemm_k<<<dim3(1, MB), 256, 0, stream>>>(x, W_l1, nullptr, xw1, NN, 64, 256);
  gemm_k<<<dim3(1, MB), 256, 0, stream>>>(x, W_r1, b_l1, xr1, NN, 64, 256);
  hipMemsetAsync(agg1, 0, (size_t)NN * 64 * sizeof(float), stream);
  k_gather<6><<<nb((long long)NE * 64), 256, 0, stream>>>(src, dst, xw1, agg1);
  k_sage_combine<6, true><<<nb((long long)NN * 64), 256, 0, stream>>>(agg1, cnt, xr1, resx, h1);

  // ---- SAGE2 ----
  gemm_k<<<dim3(2, MB), 256, 0, stream>>>(h1, W_l2, nullptr, hw2, NN, 128, 64);
  gemm_k<<<dim3(2, MB), 256, 0, stream>>>(h1, W_r2, b_l2, hr2, NN, 128, 64);
  hipMemsetAsync(agg2, 0, (size_t)NN * 128 * sizeof(float), stream);
  k_gather<7><<<nb((long long)NE * 128), 256, 0, stream>>>(src, dst, hw2, agg2);
  k_sage_combine<7, false><<<nb((long long)NN * 128), 256, 0, stream>>>(agg2, cnt, hr2, nullptr, h2);

  // ---- GAT ----
  gemm_k<<<dim3(16, MB), 256, 0, stream>>>(h2, W_g, nullptr, hg, NN, 1024, 128);
  k_gat_scores<<<nb((long long)NN * 8 * 64), 256, 0, stream>>>(hg, att_s, att_d, a_s, a_d);
  k_minit<<<nb(NN * 8), 256, 0, stream>>>(menc);
  k_gat_max<<<nb((long long)NEF * 8), 256, 0, stream>>>(src, dst, a_s, a_d, menc);
  hipMemsetAsync(denom, 0, (size_t)NN * 8 * sizeof(float), stream);
  k_gat_exp<<<nb((long long)NEF * 8), 256, 0, stream>>>(src, dst, a_s, a_d, menc, ee, denom);
  k_gat_alpha<<<nb((long long)NEF * 8), 256, 0, stream>>>(dst, ee, denom);
  hipMemsetAsync(gat, 0, (size_t)NN * 1024 * sizeof(float), stream);  // after hg GEMM consumed h2
  k_gat_agg<<<nb((long long)NEF * 1024), 256, 0, stream>>>(src, dst, ee, hg, gat);
  k_bias_relu<<<nb((long long)NN * 1024), 256, 0, stream>>>(gat, b_g);

  // ---- GCN1 ----
  k_dinv<<<nb(NN), 256, 0, stream>>>(cnt, dinv);
  gemm_k<<<dim3(1, MB), 256, 0, stream>>>(gat, W_c1, nullptr, hw64, NN, 64, 1024);
  hipMemsetAsync(acc64, 0, (size_t)NN * 64 * sizeof(float), stream);
  k_gcn_agg<6><<<nb((long long)NEF * 64), 256, 0, stream>>>(src, dst, dinv, hw64, acc64);
  k_add_bias<6><<<nb((long long)NN * 64), 256, 0, stream>>>(acc64, b_c1);

  // ---- GCN2 + log_softmax ----
  gemm_k<<<dim3(1, MB), 256, 0, stream>>>(acc64, W_c2, nullptr, hw32, NN, 32, 64);
  hipMemsetAsync(acc32, 0, (size_t)NN * 32 * sizeof(float), stream);
  k_gcn_agg<5><<<nb((long long)NEF * 32), 256, 0, stream>>>(src, dst, dinv, hw32, acc32);
  k_logsoftmax<<<nb(NN), 256, 0, stream>>>(acc32, b_c2, out);
}

// Round 2
// 776.996 us; speedup vs baseline: 1.7086x; 1.7086x over previous
//
#include <hip/hip_runtime.h>

#define NN 20000
#define NE 160000
#define NEF 180000  // edges + self loops

typedef long long ll;

// ---------- ordered-float encoding for atomicMax on possibly-negative floats ----
static __device__ __forceinline__ unsigned enc_f(float f) {
  unsigned u = __float_as_uint(f);
  return (u & 0x80000000u) ? ~u : (u | 0x80000000u);
}
static __device__ __forceinline__ float dec_f(unsigned e) {
  return (e & 0x80000000u) ? __uint_as_float(e & 0x7fffffffu) : __uint_as_float(~e);
}

// ---------- generic f32 GEMM: C[M,N] = A[M,K] @ B[K,N] (+bias) ----------
__global__ __launch_bounds__(256) void gemm_k(
    const float* __restrict__ A, const float* __restrict__ B,
    const float* __restrict__ bias, float* __restrict__ C,
    int M, int N, int K)
{
  __shared__ float As[16][65];
  __shared__ float Bs[16][65];
  const int bn = blockIdx.x * 64;
  const int bm = blockIdx.y * 64;
  const int tid = threadIdx.x;
  const int tx = tid & 15;
  const int ty = tid >> 4;
  float acc[4][4] = {{0.f}};
  for (int k0 = 0; k0 < K; k0 += 16) {
    #pragma unroll
    for (int i = 0; i < 4; i++) {
      int idx = tid + i * 256;
      int m = idx >> 4, k = idx & 15;
      int gm = bm + m;
      As[k][m] = (gm < M) ? A[(ll)gm * K + (k0 + k)] : 0.f;
    }
    #pragma unroll
    for (int i = 0; i < 4; i++) {
      int idx = tid + i * 256;
      int k = idx >> 6, n = idx & 63;
      int gn = bn + n;
      Bs[k][n] = (gn < N) ? B[(ll)(k0 + k) * N + gn] : 0.f;
    }
    __syncthreads();
    #pragma unroll
    for (int k = 0; k < 16; k++) {
      float a[4], b[4];
      #pragma unroll
      for (int i = 0; i < 4; i++) a[i] = As[k][ty * 4 + i];
      #pragma unroll
      for (int j = 0; j < 4; j++) b[j] = Bs[k][tx * 4 + j];
      #pragma unroll
      for (int i = 0; i < 4; i++)
        #pragma unroll
        for (int j = 0; j < 4; j++)
          acc[i][j] = fmaf(a[i], b[j], acc[i][j]);
    }
    __syncthreads();
  }
  #pragma unroll
  for (int i = 0; i < 4; i++) {
    int gm = bm + ty * 4 + i;
    if (gm >= M) continue;
    #pragma unroll
    for (int j = 0; j < 4; j++) {
      int gn = bn + tx * 4 + j;
      if (gn >= N) continue;
      float v = acc[i][j];
      if (bias) v += bias[gn];
      C[(ll)gm * N + gn] = v;
    }
  }
}

// ---------- CSR build ----------
__global__ void k_counti(const int* __restrict__ dst, int* __restrict__ icnt) {
  int e = blockIdx.x * 256 + threadIdx.x;
  if (e < NE) atomicAdd(&icnt[dst[e]], 1);
}

// single-block exclusive scan of (icnt[i]+1) over NN entries -> rowptr, cur
__global__ __launch_bounds__(1024) void k_scan(const int* __restrict__ icnt,
                                               int* __restrict__ rowptr,
                                               int* __restrict__ cur) {
  __shared__ int sd[1024];
  __shared__ int carry_s;
  int tid = threadIdx.x;
  if (tid == 0) carry_s = 0;
  __syncthreads();
  for (int base = 0; base < NN; base += 1024) {
    int i = base + tid;
    int v = (i < NN) ? icnt[i] + 1 : 0;   // +1 self loop
    sd[tid] = v;
    __syncthreads();
    for (int o = 1; o < 1024; o <<= 1) {
      int t = (tid >= o) ? sd[tid - o] : 0;
      __syncthreads();
      sd[tid] += t;
      __syncthreads();
    }
    int c = carry_s;
    int excl = c + sd[tid] - v;
    if (i < NN) { rowptr[i] = excl; cur[i] = excl; }
    int tot = sd[1023];
    __syncthreads();
    if (tid == 0) carry_s = c + tot;
    __syncthreads();
  }
  if (tid == 0) rowptr[NN] = carry_s;
}

// scatter edge ids (0..NE-1 real, NE..NEF-1 self loops) into CSR order by dst
__global__ void k_scatter(const int* __restrict__ dst, int* __restrict__ cur,
                          int* __restrict__ eid) {
  int t = blockIdx.x * 256 + threadIdx.x;
  if (t >= NEF) return;
  int d = (t < NE) ? dst[t] : t - NE;
  int p = atomicAdd(&cur[d], 1);
  eid[p] = t;
}

// ---------- fused SAGE aggregation (mean over real edges) + lin_r + relu (+res) ----
template<int C, bool ADD_RES>   // C = 64 or 128
__global__ __launch_bounds__(256) void k_sage_csr(
    const int* __restrict__ rowptr, const int* __restrict__ eid,
    const int* __restrict__ src, const float* __restrict__ feat,
    const float* __restrict__ linr, const float* __restrict__ resx,
    float* __restrict__ out)
{
  int node = blockIdx.x * 4 + (threadIdx.x >> 6);
  int lane = threadIdx.x & 63;
  if (node >= NN) return;
  int b = rowptr[node], e = rowptr[node + 1];
  float a0 = 0.f, a1 = 0.f;
  int n = 0;
  for (int p = b; p < e; p++) {
    int ed = eid[p];
    if (ed >= NE) continue;            // self loop: not part of SAGE neighborhood
    int s = src[ed];
    a0 += feat[(ll)s * C + lane];
    if (C == 128) a1 += feat[(ll)s * C + lane + 64];
    n++;
  }
  float inv = 1.f / fmaxf((float)n, 1.f);
  {
    float v = a0 * inv + linr[(ll)node * C + lane];
    v = fmaxf(v, 0.f);
    if (ADD_RES) v += resx[(ll)node * C + lane];
    out[(ll)node * C + lane] = v;
  }
  if (C == 128) {
    float v = a1 * inv + linr[(ll)node * C + lane + 64];
    v = fmaxf(v, 0.f);
    out[(ll)node * C + lane + 64] = v;
  }
}

// ---------- GAT score/softmax prep ----------
__global__ void k_gat_scores(const float* __restrict__ hg, const float* __restrict__ att_s,
                             const float* __restrict__ att_d, float* __restrict__ a_s,
                             float* __restrict__ a_d) {
  int gtid = blockIdx.x * 256 + threadIdx.x;
  int row = gtid >> 6;          // i*8 + h
  int lane = threadIdx.x & 63;
  if (row >= NN * 8) return;
  int h = row & 7;
  const float* r = hg + (ll)row * 128;
  float v0 = r[lane], v1 = r[lane + 64];
  float s = v0 * att_s[h * 128 + lane] + v1 * att_s[h * 128 + lane + 64];
  float d = v0 * att_d[h * 128 + lane] + v1 * att_d[h * 128 + lane + 64];
  #pragma unroll
  for (int o = 32; o > 0; o >>= 1) { s += __shfl_down(s, o); d += __shfl_down(d, o); }
  if (lane == 0) { a_s[row] = s; a_d[row] = d; }
}

__global__ void k_minit(unsigned* __restrict__ m) {
  int t = blockIdx.x * 256 + threadIdx.x;
  if (t < NN * 8) m[t] = enc_f(-3.0e38f);
}

static __device__ __forceinline__ void ef_sd(int ef, const int* src, const int* dst, int& s, int& d) {
  if (ef < NE) { s = src[ef]; d = dst[ef]; } else { s = d = ef - NE; }
}

__global__ void k_gat_max(const int* __restrict__ src, const int* __restrict__ dst,
                          const float* __restrict__ a_s, const float* __restrict__ a_d,
                          unsigned* __restrict__ m) {
  int t = blockIdx.x * 256 + threadIdx.x;
  if (t >= NEF * 8) return;
  int ef = t >> 3, h = t & 7;
  int s, d; ef_sd(ef, src, dst, s, d);
  float e = a_s[s * 8 + h] + a_d[d * 8 + h];
  e = (e > 0.f) ? e : 0.2f * e;
  atomicMax(&m[d * 8 + h], enc_f(e));
}

__global__ void k_gat_exp(const int* __restrict__ src, const int* __restrict__ dst,
                          const float* __restrict__ a_s, const float* __restrict__ a_d,
                          const unsigned* __restrict__ m, float* __restrict__ ee,
                          float* __restrict__ denom) {
  int t = blockIdx.x * 256 + threadIdx.x;
  if (t >= NEF * 8) return;
  int ef = t >> 3, h = t & 7;
  int s, d; ef_sd(ef, src, dst, s, d);
  float e = a_s[s * 8 + h] + a_d[d * 8 + h];
  e = (e > 0.f) ? e : 0.2f * e;
  float v = expf(e - dec_f(m[d * 8 + h]));
  ee[t] = v;
  atomicAdd(&denom[d * 8 + h], v);
}

// ---------- fused GAT aggregation: alpha=ee/denom, += bias, relu ----------
__global__ __launch_bounds__(256) void k_gat_csr(
    const int* __restrict__ rowptr, const int* __restrict__ eid,
    const int* __restrict__ src, const float* __restrict__ ee,
    const float* __restrict__ denom, const float4* __restrict__ hg4,
    const float* __restrict__ b_g, float4* __restrict__ gat4)
{
  int node = blockIdx.x;
  int t = threadIdx.x;         // one float4 (4 channels) per thread; 256*4 = 1024 ch
  int h = t >> 5;              // head = (4t)/128
  float dv = denom[node * 8 + h];
  float4 acc = make_float4(0.f, 0.f, 0.f, 0.f);
  int b = rowptr[node], e = rowptr[node + 1];
  for (int p = b; p < e; p++) {
    int ed = eid[p];
    int s = (ed < NE) ? src[ed] : node;
    float a = ee[(ll)ed * 8 + h];
    float4 v = hg4[(ll)s * 256 + t];
    acc.x = fmaf(a, v.x, acc.x);
    acc.y = fmaf(a, v.y, acc.y);
    acc.z = fmaf(a, v.z, acc.z);
    acc.w = fmaf(a, v.w, acc.w);
  }
  float inv = 1.f / dv;
  float4 bb = ((const float4*)b_g)[t];
  float4 o;
  o.x = fmaxf(fmaf(acc.x, inv, bb.x), 0.f);
  o.y = fmaxf(fmaf(acc.y, inv, bb.y), 0.f);
  o.z = fmaxf(fmaf(acc.z, inv, bb.z), 0.f);
  o.w = fmaxf(fmaf(acc.w, inv, bb.w), 0.f);
  gat4[(ll)node * 256 + t] = o;
}

// ---------- GCN ----------
__global__ void k_dinv(const int* __restrict__ icnt, float* __restrict__ dinv) {
  int i = blockIdx.x * 256 + threadIdx.x;
  if (i < NN) dinv[i] = rsqrtf((float)icnt[i] + 1.0f);   // +1 self loop
}

// fused symmetric-norm aggregation + bias. C=64: wave per node (lane=ch).
// C=32: half-wave per node.
template<int C>
__global__ __launch_bounds__(256) void k_gcn_csr(
    const int* __restrict__ rowptr, const int* __restrict__ eid,
    const int* __restrict__ src, const float* __restrict__ dinv,
    const float* __restrict__ hw, const float* __restrict__ bias,
    float* __restrict__ out)
{
  int npb = 256 / C;
  int node = blockIdx.x * npb + threadIdx.x / C;
  int c = threadIdx.x & (C - 1);
  if (node >= NN) return;
  int b = rowptr[node], e = rowptr[node + 1];
  float acc = 0.f;
  for (int p = b; p < e; p++) {
    int ed = eid[p];
    int s = (ed < NE) ? src[ed] : node;
    acc = fmaf(dinv[s], hw[(ll)s * C + c], acc);
  }
  out[(ll)node * C + c] = acc * dinv[node] + bias[c];
}

__global__ void k_logsoftmax(const float* __restrict__ acc, float* __restrict__ out) {
  int i = blockIdx.x * 256 + threadIdx.x;
  if (i >= NN) return;
  float v[32]; float mx = -3e38f;
  #pragma unroll
  for (int c = 0; c < 32; c++) { v[c] = acc[i * 32 + c]; mx = fmaxf(mx, v[c]); }
  float s = 0.f;
  #pragma unroll
  for (int c = 0; c < 32; c++) s += expf(v[c] - mx);
  float ls = logf(s) + mx;
  #pragma unroll
  for (int c = 0; c < 32; c++) out[i * 32 + c] = v[c] - ls;
}

extern "C" void kernel_launch(void* const* d_in, const int* in_sizes, int n_in,
                              void* d_out, int out_size, void* d_ws, size_t ws_size,
                              hipStream_t stream) {
  const float* x     = (const float*)d_in[0];
  const int*   ei    = (const int*)d_in[1];
  const float* W_l1  = (const float*)d_in[2];
  const float* b_l1  = (const float*)d_in[3];
  const float* W_r1  = (const float*)d_in[4];
  const float* W_l2  = (const float*)d_in[5];
  const float* b_l2  = (const float*)d_in[6];
  const float* W_r2  = (const float*)d_in[7];
  const float* W_g   = (const float*)d_in[8];
  const float* att_s = (const float*)d_in[9];
  const float* att_d = (const float*)d_in[10];
  const float* b_g   = (const float*)d_in[11];
  const float* W_c1  = (const float*)d_in[12];
  const float* b_c1  = (const float*)d_in[13];
  const float* W_c2  = (const float*)d_in[14];
  const float* b_c2  = (const float*)d_in[15];
  const float* W_res = (const float*)d_in[16];
  const float* b_res = (const float*)d_in[17];
  const int* src = ei;
  const int* dst = ei + NE;
  float* out = (float*)d_out;

  // ---- workspace layout (floats) ----
  float* Wf = (float*)d_ws;
  size_t off = 0;
  auto take = [&](size_t n) { float* p = Wf + off; off += n; return p; };
  float* BIG0  = take((size_t)NN * 1024);   // xw1/xr1 -> hw2/hr2 -> hg
  float* BIG1  = take((size_t)NN * 1024);   // resx/h1/h2 -> gat (=h3)
  int*   icnt  = (int*)take(NN);
  int*   rowptr= (int*)take(NN + 1);
  int*   cur   = (int*)take(NN);
  int*   eidb  = (int*)take(NEF);
  float* dinv  = take(NN);
  float* a_s   = take((size_t)NN * 8);
  float* a_d   = take((size_t)NN * 8);
  unsigned* menc = (unsigned*)take((size_t)NN * 8);
  float* denom = take((size_t)NN * 8);
  float* ee    = take((size_t)NEF * 8);
  float* hw64  = take((size_t)NN * 64);
  float* acc64 = take((size_t)NN * 64);
  float* hw32  = take((size_t)NN * 32);
  float* acc32 = take((size_t)NN * 32);
  (void)ws_size; (void)in_sizes; (void)n_in; (void)out_size;

  float* xw1  = BIG0;
  float* xr1  = BIG0 + (size_t)NN * 64;
  float* hw2  = BIG0;
  float* hr2  = BIG0 + (size_t)NN * 128;
  float* hg   = BIG0;
  float* resx = BIG1;
  float* h1   = BIG1 + (size_t)NN * 64;
  float* h2   = BIG1 + (size_t)NN * 128;
  float* gat  = BIG1;

  auto nb = [](ll t) { return dim3((unsigned)((t + 255) / 256)); };
  const unsigned MB = (NN + 63) / 64;

  // ---- CSR build (by dst, incl. self loops) ----
  hipMemsetAsync(icnt, 0, NN * sizeof(int), stream);
  k_counti<<<nb(NE), 256, 0, stream>>>(dst, icnt);
  k_scan<<<1, 1024, 0, stream>>>(icnt, rowptr, cur);
  k_scatter<<<nb(NEF), 256, 0, stream>>>(dst, cur, eidb);
  k_dinv<<<nb(NN), 256, 0, stream>>>(icnt, dinv);

  // ---- SAGE1 + residual ----
  gemm_k<<<dim3(1, MB), 256, 0, stream>>>(x, W_res, b_res, resx, NN, 64, 256);
  gemm_k<<<dim3(1, MB), 256, 0, stream>>>(x, W_l1, nullptr, xw1, NN, 64, 256);
  gemm_k<<<dim3(1, MB), 256, 0, stream>>>(x, W_r1, b_l1, xr1, NN, 64, 256);
  k_sage_csr<64, true><<<nb((ll)NN * 64), 256, 0, stream>>>(rowptr, eidb, src, xw1, xr1, resx, h1);

  // ---- SAGE2 ----
  gemm_k<<<dim3(2, MB), 256, 0, stream>>>(h1, W_l2, nullptr, hw2, NN, 128, 64);
  gemm_k<<<dim3(2, MB), 256, 0, stream>>>(h1, W_r2, b_l2, hr2, NN, 128, 64);
  k_sage_csr<128, false><<<nb((ll)NN * 64), 256, 0, stream>>>(rowptr, eidb, src, hw2, hr2, nullptr, h2);

  // ---- GAT ----
  gemm_k<<<dim3(16, MB), 256, 0, stream>>>(h2, W_g, nullptr, hg, NN, 1024, 128);
  k_gat_scores<<<nb((ll)NN * 8 * 64), 256, 0, stream>>>(hg, att_s, att_d, a_s, a_d);
  k_minit<<<nb(NN * 8), 256, 0, stream>>>(menc);
  k_gat_max<<<nb((ll)NEF * 8), 256, 0, stream>>>(src, dst, a_s, a_d, menc);
  hipMemsetAsync(denom, 0, (size_t)NN * 8 * sizeof(float), stream);
  k_gat_exp<<<nb((ll)NEF * 8), 256, 0, stream>>>(src, dst, a_s, a_d, menc, ee, denom);
  k_gat_csr<<<dim3(NN), 256, 0, stream>>>(rowptr, eidb, src, ee, denom,
                                          (const float4*)hg, b_g, (float4*)gat);

  // ---- GCN1 ----
  gemm_k<<<dim3(1, MB), 256, 0, stream>>>(gat, W_c1, nullptr, hw64, NN, 64, 1024);
  k_gcn_csr<64><<<nb((ll)NN * 64), 256, 0, stream>>>(rowptr, eidb, src, dinv, hw64, b_c1, acc64);

  // ---- GCN2 + log_softmax ----
  gemm_k<<<dim3(1, MB), 256, 0, stream>>>(acc64, W_c2, nullptr, hw32, NN, 32, 64);
  k_gcn_csr<32><<<nb((ll)NN * 32), 256, 0, stream>>>(rowptr, eidb, src, dinv, hw32, b_c2, acc32);
  k_logsoftmax<<<nb(NN), 256, 0, stream>>>(acc32, out);
}

// Round 3
// 439.008 us; speedup vs baseline: 3.0240x; 1.7699x over previous
//
#include <hip/hip_runtime.h>

#define NN 20000
#define NE 160000
#define NEF 180000  // edges + self loops

typedef long long ll;
typedef __attribute__((ext_vector_type(4))) float f32x4;
typedef __attribute__((ext_vector_type(8))) short s16x8;

// ---------- bf16 helpers (manual, round-to-nearest-even) ----------
static __device__ __forceinline__ float b2f(ushort u) {
  return __uint_as_float(((unsigned)u) << 16);
}
static __device__ __forceinline__ ushort f2b(float f) {
  unsigned u = __float_as_uint(f);
  return (ushort)((u + 0x7fffu + ((u >> 16) & 1u)) >> 16);
}

// ---------- ordered-float encoding for atomicMax on possibly-negative floats ----
static __device__ __forceinline__ unsigned enc_f(float f) {
  unsigned u = __float_as_uint(f);
  return (u & 0x80000000u) ? ~u : (u | 0x80000000u);
}
static __device__ __forceinline__ float dec_f(unsigned e) {
  return (e & 0x80000000u) ? __uint_as_float(e & 0x7fffffffu) : __uint_as_float(~e);
}

// ---------- bf16 MFMA GEMM: C[M,N] = A[M,K] @ Bt[N,K]^T (+bias) ----------
// 256 threads = 4 waves in 2x2; each wave computes 32x32 via 2x2 16x16x32 frags.
// No LDS: direct global fragment loads (A and Bt both contiguous 16B per lane).
template<bool OUT_BF16>
__global__ __launch_bounds__(256) void gemm_mfma(
    const ushort* __restrict__ A, const ushort* __restrict__ Bt,
    const float* __restrict__ bias, void* __restrict__ Cv,
    int M, int N, int K)
{
  const int wid  = threadIdx.x >> 6;
  const int lane = threadIdx.x & 63;
  const int wr = wid >> 1, wc = wid & 1;
  const int bm = blockIdx.y * 64 + wr * 32;
  const int bn = blockIdx.x * 64 + wc * 32;
  const int lr = lane & 15;
  const int ko = (lane >> 4) * 8;

  int r0 = min(bm + lr,      M - 1);
  int r1 = min(bm + 16 + lr, M - 1);
  int c0 = min(bn + lr,      N - 1);
  int c1 = min(bn + 16 + lr, N - 1);
  const ushort* pa0 = A  + (ll)r0 * K + ko;
  const ushort* pa1 = A  + (ll)r1 * K + ko;
  const ushort* pb0 = Bt + (ll)c0 * K + ko;
  const ushort* pb1 = Bt + (ll)c1 * K + ko;

  f32x4 acc00 = {0.f,0.f,0.f,0.f}, acc01 = acc00, acc10 = acc00, acc11 = acc00;

  #pragma unroll 4
  for (int k = 0; k < K; k += 32) {
    s16x8 a0 = *(const s16x8*)(pa0 + k);
    s16x8 a1 = *(const s16x8*)(pa1 + k);
    s16x8 b0 = *(const s16x8*)(pb0 + k);
    s16x8 b1 = *(const s16x8*)(pb1 + k);
    acc00 = __builtin_amdgcn_mfma_f32_16x16x32_bf16(a0, b0, acc00, 0, 0, 0);
    acc01 = __builtin_amdgcn_mfma_f32_16x16x32_bf16(a0, b1, acc01, 0, 0, 0);
    acc10 = __builtin_amdgcn_mfma_f32_16x16x32_bf16(a1, b0, acc10, 0, 0, 0);
    acc11 = __builtin_amdgcn_mfma_f32_16x16x32_bf16(a1, b1, acc11, 0, 0, 0);
  }

  const int rq = (lane >> 4) * 4;
  #pragma unroll
  for (int i = 0; i < 2; i++) {
    #pragma unroll
    for (int j = 0; j < 2; j++) {
      f32x4 a = (i == 0) ? (j == 0 ? acc00 : acc01) : (j == 0 ? acc10 : acc11);
      int col = bn + j * 16 + lr;
      if (col >= N) continue;
      float bv = bias ? bias[col] : 0.f;
      int rbase = bm + i * 16 + rq;
      #pragma unroll
      for (int r = 0; r < 4; r++) {
        int row = rbase + r;
        if (row >= M) continue;
        float v = a[r] + bv;
        if (OUT_BF16) ((ushort*)Cv)[(ll)row * N + col] = f2b(v);
        else          ((float*)Cv)[(ll)row * N + col] = v;
      }
    }
  }
}

// ---------- casts & weight prep ----------
__global__ void k_cast(const float* __restrict__ in, ushort* __restrict__ outb, ll n) {
  ll t = ((ll)blockIdx.x * 256 + threadIdx.x) * 4;
  if (t >= n) return;
  float4 v = *(const float4*)(in + t);
  ushort4 o;
  o.x = f2b(v.x); o.y = f2b(v.y); o.z = f2b(v.z); o.w = f2b(v.w);
  *(ushort4*)(outb + t) = o;
}

struct PrepEnt { const float* W; ushort* Bt; int N; int K; int base; };
struct Prep { PrepEnt e[8]; int total; };

__global__ void k_prep(Prep p) {   // Bt[n*K+k] = bf16(W[k*N+n])
  int t = blockIdx.x * 256 + threadIdx.x;
  if (t >= p.total) return;
  #pragma unroll
  for (int i = 0; i < 8; i++) {
    int sz = p.e[i].N * p.e[i].K;
    if (t >= p.e[i].base && t < p.e[i].base + sz) {
      int loc = t - p.e[i].base;
      int n = loc / p.e[i].K, k = loc - n * p.e[i].K;
      p.e[i].Bt[loc] = f2b(p.e[i].W[(ll)k * p.e[i].N + n]);
    }
  }
}

__global__ void k_biasprep(const float* __restrict__ b_res, const float* __restrict__ b_l1,
                           const float* __restrict__ b_l2, float* __restrict__ bias192,
                           float* __restrict__ bias256) {
  int t = threadIdx.x;
  if (t < 64) bias192[t] = b_res[t];
  else if (t < 128) bias192[t] = 0.f;
  else if (t < 192) bias192[t] = b_l1[t - 128];
  bias256[t] = (t < 128) ? 0.f : b_l2[t - 128];
}

// ---------- CSR build ----------
__global__ void k_counti(const int* __restrict__ dst, int* __restrict__ icnt) {
  int e = blockIdx.x * 256 + threadIdx.x;
  if (e < NE) atomicAdd(&icnt[dst[e]], 1);
}

__global__ __launch_bounds__(1024) void k_scan(const int* __restrict__ icnt,
                                               int* __restrict__ rowptr,
                                               int* __restrict__ cur) {
  __shared__ int sd[1024];
  __shared__ int carry_s;
  int tid = threadIdx.x;
  if (tid == 0) carry_s = 0;
  __syncthreads();
  for (int base = 0; base < NN; base += 1024) {
    int i = base + tid;
    int v = (i < NN) ? icnt[i] + 1 : 0;   // +1 self loop
    sd[tid] = v;
    __syncthreads();
    for (int o = 1; o < 1024; o <<= 1) {
      int t = (tid >= o) ? sd[tid - o] : 0;
      __syncthreads();
      sd[tid] += t;
      __syncthreads();
    }
    int c = carry_s;
    int excl = c + sd[tid] - v;
    if (i < NN) { rowptr[i] = excl; cur[i] = excl; }
    int tot = sd[1023];
    __syncthreads();
    if (tid == 0) carry_s = c + tot;
    __syncthreads();
  }
  if (tid == 0) rowptr[NN] = carry_s;
}

__global__ void k_scatter(const int* __restrict__ dst, int* __restrict__ cur,
                          int* __restrict__ eid) {
  int t = blockIdx.x * 256 + threadIdx.x;
  if (t >= NEF) return;
  int d = (t < NE) ? dst[t] : t - NE;
  int p = atomicAdd(&cur[d], 1);
  eid[p] = t;
}

__global__ void k_dinv(const int* __restrict__ icnt, float* __restrict__ dinv) {
  int i = blockIdx.x * 256 + threadIdx.x;
  if (i < NN) dinv[i] = rsqrtf((float)icnt[i] + 1.0f);
}

// ---------- fused SAGE aggregation (bf16 in/out, strided slices) ----------
template<int C, int STRIDE, bool ADD_RES>
__global__ __launch_bounds__(256) void k_sage_csr(
    const int* __restrict__ rowptr, const int* __restrict__ eid,
    const int* __restrict__ src, const ushort* __restrict__ feat,
    const ushort* __restrict__ linr, const ushort* __restrict__ resx,
    ushort* __restrict__ out)
{
  int node = blockIdx.x * 4 + (threadIdx.x >> 6);
  int lane = threadIdx.x & 63;
  if (node >= NN) return;
  int b = rowptr[node], e = rowptr[node + 1];
  float a0 = 0.f, a1 = 0.f;
  int n = 0;
  for (int p = b; p < e; p++) {
    int ed = eid[p];
    if (ed >= NE) continue;            // self loop not in SAGE neighborhood
    int s = src[ed];
    a0 += b2f(feat[(ll)s * STRIDE + lane]);
    if (C == 128) a1 += b2f(feat[(ll)s * STRIDE + lane + 64]);
    n++;
  }
  float inv = 1.f / fmaxf((float)n, 1.f);
  {
    float v = a0 * inv + b2f(linr[(ll)node * STRIDE + lane]);
    v = fmaxf(v, 0.f);
    if (ADD_RES) v += b2f(resx[(ll)node * STRIDE + lane]);
    out[(ll)node * C + lane] = f2b(v);
  }
  if (C == 128) {
    float v = a1 * inv + b2f(linr[(ll)node * STRIDE + lane + 64]);
    v = fmaxf(v, 0.f);
    out[(ll)node * C + lane + 64] = f2b(v);
  }
}

// ---------- GAT scores (bf16 hg) ----------
__global__ void k_gat_scores(const ushort* __restrict__ hg, const float* __restrict__ att_s,
                             const float* __restrict__ att_d, float* __restrict__ a_s,
                             float* __restrict__ a_d) {
  int gtid = blockIdx.x * 256 + threadIdx.x;
  int row = gtid >> 6;          // i*8 + h
  int lane = threadIdx.x & 63;
  if (row >= NN * 8) return;
  int h = row & 7;
  const ushort* r = hg + (ll)row * 128;
  float v0 = b2f(r[lane]), v1 = b2f(r[lane + 64]);
  float s = v0 * att_s[h * 128 + lane] + v1 * att_s[h * 128 + lane + 64];
  float d = v0 * att_d[h * 128 + lane] + v1 * att_d[h * 128 + lane + 64];
  #pragma unroll
  for (int o = 32; o > 0; o >>= 1) { s += __shfl_down(s, o); d += __shfl_down(d, o); }
  if (lane == 0) { a_s[row] = s; a_d[row] = d; }
}

__global__ void k_minit(unsigned* __restrict__ m) {
  int t = blockIdx.x * 256 + threadIdx.x;
  if (t < NN * 8) m[t] = enc_f(-3.0e38f);
}

static __device__ __forceinline__ void ef_sd(int ef, const int* src, const int* dst, int& s, int& d) {
  if (ef < NE) { s = src[ef]; d = dst[ef]; } else { s = d = ef - NE; }
}

__global__ void k_gat_max(const int* __restrict__ src, const int* __restrict__ dst,
                          const float* __restrict__ a_s, const float* __restrict__ a_d,
                          unsigned* __restrict__ m) {
  int t = blockIdx.x * 256 + threadIdx.x;
  if (t >= NEF * 8) return;
  int ef = t >> 3, h = t & 7;
  int s, d; ef_sd(ef, src, dst, s, d);
  float e = a_s[s * 8 + h] + a_d[d * 8 + h];
  e = (e > 0.f) ? e : 0.2f * e;
  atomicMax(&m[d * 8 + h], enc_f(e));
}

__global__ void k_gat_exp(const int* __restrict__ src, const int* __restrict__ dst,
                          const float* __restrict__ a_s, const float* __restrict__ a_d,
                          const unsigned* __restrict__ m, float* __restrict__ ee,
                          float* __restrict__ denom) {
  int t = blockIdx.x * 256 + threadIdx.x;
  if (t >= NEF * 8) return;
  int ef = t >> 3, h = t & 7;
  int s, d; ef_sd(ef, src, dst, s, d);
  float e = a_s[s * 8 + h] + a_d[d * 8 + h];
  e = (e > 0.f) ? e : 0.2f * e;
  float v = expf(e - dec_f(m[d * 8 + h]));
  ee[t] = v;
  atomicAdd(&denom[d * 8 + h], v);
}

// ---------- fused GAT aggregation (bf16 hg in, bf16 gat out) ----------
__global__ __launch_bounds__(256) void k_gat_csr(
    const int* __restrict__ rowptr, const int* __restrict__ eid,
    const int* __restrict__ src, const float* __restrict__ ee,
    const float* __restrict__ denom, const ushort4* __restrict__ hg4,
    const float* __restrict__ b_g, ushort4* __restrict__ gat4)
{
  int node = blockIdx.x;
  int t = threadIdx.x;         // 4 channels per thread; 256*4 = 1024
  int h = t >> 5;
  float dv = denom[node * 8 + h];
  float ax = 0.f, ay = 0.f, az = 0.f, aw = 0.f;
  int b = rowptr[node], e = rowptr[node + 1];
  for (int p = b; p < e; p++) {
    int ed = eid[p];
    int s = (ed < NE) ? src[ed] : node;
    float a = ee[(ll)ed * 8 + h];
    ushort4 v = hg4[(ll)s * 256 + t];
    ax = fmaf(a, b2f(v.x), ax);
    ay = fmaf(a, b2f(v.y), ay);
    az = fmaf(a, b2f(v.z), az);
    aw = fmaf(a, b2f(v.w), aw);
  }
  float inv = 1.f / dv;
  float4 bb = ((const float4*)b_g)[t];
  ushort4 o;
  o.x = f2b(fmaxf(fmaf(ax, inv, bb.x), 0.f));
  o.y = f2b(fmaxf(fmaf(ay, inv, bb.y), 0.f));
  o.z = f2b(fmaxf(fmaf(az, inv, bb.z), 0.f));
  o.w = f2b(fmaxf(fmaf(aw, inv, bb.w), 0.f));
  gat4[(ll)node * 256 + t] = o;
}

// ---------- GCN aggregation (bf16 feat; out bf16 or f32) ----------
template<int C, bool OUTF32>
__global__ __launch_bounds__(256) void k_gcn_csr(
    const int* __restrict__ rowptr, const int* __restrict__ eid,
    const int* __restrict__ src, const float* __restrict__ dinv,
    const ushort* __restrict__ hw, const float* __restrict__ bias,
    void* __restrict__ outv)
{
  int npb = 256 / C;
  int node = blockIdx.x * npb + threadIdx.x / C;
  int c = threadIdx.x & (C - 1);
  if (node >= NN) return;
  int b = rowptr[node], e = rowptr[node + 1];
  float acc = 0.f;
  for (int p = b; p < e; p++) {
    int ed = eid[p];
    int s = (ed < NE) ? src[ed] : node;
    acc = fmaf(dinv[s], b2f(hw[(ll)s * C + c]), acc);
  }
  float v = acc * dinv[node] + bias[c];
  if (OUTF32) ((float*)outv)[(ll)node * C + c] = v;
  else        ((ushort*)outv)[(ll)node * C + c] = f2b(v);
}

__global__ void k_logsoftmax(const float* __restrict__ acc, float* __restrict__ out) {
  int i = blockIdx.x * 256 + threadIdx.x;
  if (i >= NN) return;
  float v[32]; float mx = -3e38f;
  #pragma unroll
  for (int c = 0; c < 32; c++) { v[c] = acc[i * 32 + c]; mx = fmaxf(mx, v[c]); }
  float s = 0.f;
  #pragma unroll
  for (int c = 0; c < 32; c++) s += expf(v[c] - mx);
  float ls = logf(s) + mx;
  #pragma unroll
  for (int c = 0; c < 32; c++) out[i * 32 + c] = v[c] - ls;
}

extern "C" void kernel_launch(void* const* d_in, const int* in_sizes, int n_in,
                              void* d_out, int out_size, void* d_ws, size_t ws_size,
                              hipStream_t stream) {
  const float* x     = (const float*)d_in[0];
  const int*   ei    = (const int*)d_in[1];
  const float* W_l1  = (const float*)d_in[2];
  const float* b_l1  = (const float*)d_in[3];
  const float* W_r1  = (const float*)d_in[4];
  const float* W_l2  = (const float*)d_in[5];
  const float* b_l2  = (const float*)d_in[6];
  const float* W_r2  = (const float*)d_in[7];
  const float* W_g   = (const float*)d_in[8];
  const float* att_s = (const float*)d_in[9];
  const float* att_d = (const float*)d_in[10];
  const float* b_g   = (const float*)d_in[11];
  const float* W_c1  = (const float*)d_in[12];
  const float* b_c1  = (const float*)d_in[13];
  const float* W_c2  = (const float*)d_in[14];
  const float* b_c2  = (const float*)d_in[15];
  const float* W_res = (const float*)d_in[16];
  const float* b_res = (const float*)d_in[17];
  const int* src = ei;
  const int* dst = ei + NE;
  float* out = (float*)d_out;

  // ---- workspace layout (4-byte units) ----
  float* Wf = (float*)d_ws;
  size_t off = 0;
  auto take = [&](size_t n) { float* p = Wf + off; off += (n + 3) & ~(size_t)3; return p; };
  ushort* xb    = (ushort*)take((size_t)NN * 128);   // x bf16 [NN,256]
  ushort* C192  = (ushort*)take((size_t)NN * 96);    // [resx|xw1|xr1] bf16
  ushort* h1    = (ushort*)take((size_t)NN * 32);    // [NN,64]
  ushort* C256  = (ushort*)take((size_t)NN * 128);   // [hw2|hr2] bf16
  ushort* h2    = (ushort*)take((size_t)NN * 64);    // [NN,128]
  ushort* hg    = (ushort*)take((size_t)NN * 512);   // [NN,1024]
  ushort* gat   = (ushort*)take((size_t)NN * 512);   // [NN,1024]
  ushort* hw64  = (ushort*)take((size_t)NN * 32);
  ushort* acc64 = (ushort*)take((size_t)NN * 32);
  ushort* hw32  = (ushort*)take((size_t)NN * 16);
  float*  acc32 = take((size_t)NN * 32);
  ushort* Bt192 = (ushort*)take(192 * 256 / 2);
  ushort* Bt256 = (ushort*)take(256 * 64 / 2);
  ushort* BtG   = (ushort*)take(1024 * 128 / 2);
  ushort* Btc1  = (ushort*)take(64 * 1024 / 2);
  ushort* Btc2  = (ushort*)take(32 * 64 / 2);
  float* bias192 = take(192);
  float* bias256 = take(256);
  int*   icnt   = (int*)take(NN);
  int*   rowptr = (int*)take(NN + 1);
  int*   cur    = (int*)take(NN);
  int*   eidb   = (int*)take(NEF);
  float* dinv   = take(NN);
  float* a_s    = take((size_t)NN * 8);
  float* a_d    = take((size_t)NN * 8);
  unsigned* menc = (unsigned*)take((size_t)NN * 8);
  float* denom  = take((size_t)NN * 8);
  float* ee     = take((size_t)NEF * 8);
  (void)ws_size; (void)in_sizes; (void)n_in; (void)out_size;

  auto nb = [](ll t) { return dim3((unsigned)((t + 255) / 256)); };
  const unsigned MB = (NN + 63) / 64;   // 313

  // ---- CSR build ----
  hipMemsetAsync(icnt, 0, NN * sizeof(int), stream);
  k_counti<<<nb(NE), 256, 0, stream>>>(dst, icnt);
  k_scan<<<1, 1024, 0, stream>>>(icnt, rowptr, cur);
  k_scatter<<<nb(NEF), 256, 0, stream>>>(dst, cur, eidb);
  k_dinv<<<nb(NN), 256, 0, stream>>>(icnt, dinv);

  // ---- prep: cast x, transpose+cast weights, build bias vectors ----
  k_cast<<<nb((ll)NN * 256 / 4), 256, 0, stream>>>(x, xb, (ll)NN * 256);
  Prep pp;
  int base = 0;
  auto ent = [&](int i, const float* W, ushort* Bt, int N_, int K_) {
    pp.e[i] = {W, Bt, N_, K_, base}; base += N_ * K_;
  };
  ent(0, W_res, Bt192,             64, 256);
  ent(1, W_l1,  Bt192 + 64 * 256,  64, 256);
  ent(2, W_r1,  Bt192 + 128 * 256, 64, 256);
  ent(3, W_l2,  Bt256,             128, 64);
  ent(4, W_r2,  Bt256 + 128 * 64,  128, 64);
  ent(5, W_g,   BtG,               1024, 128);
  ent(6, W_c1,  Btc1,              64, 1024);
  ent(7, W_c2,  Btc2,              32, 64);
  pp.total = base;
  k_prep<<<nb(base), 256, 0, stream>>>(pp);
  k_biasprep<<<1, 256, 0, stream>>>(b_res, b_l1, b_l2, bias192, bias256);

  // ---- SAGE1 (+residual): one N=192 GEMM [resx|xw1|xr1] ----
  gemm_mfma<true><<<dim3(3, MB), 256, 0, stream>>>(xb, Bt192, bias192, C192, NN, 192, 256);
  k_sage_csr<64, 192, true><<<nb((ll)NN * 64), 256, 0, stream>>>(
      rowptr, eidb, src, C192 + 64, C192 + 128, C192, h1);

  // ---- SAGE2: one N=256 GEMM [hw2|hr2] ----
  gemm_mfma<true><<<dim3(4, MB), 256, 0, stream>>>(h1, Bt256, bias256, C256, NN, 256, 64);
  k_sage_csr<128, 256, false><<<nb((ll)NN * 64), 256, 0, stream>>>(
      rowptr, eidb, src, C256, C256 + 128, nullptr, h2);

  // ---- GAT ----
  gemm_mfma<true><<<dim3(16, MB), 256, 0, stream>>>(h2, BtG, nullptr, hg, NN, 1024, 128);
  k_gat_scores<<<nb((ll)NN * 8 * 64), 256, 0, stream>>>(hg, att_s, att_d, a_s, a_d);
  k_minit<<<nb(NN * 8), 256, 0, stream>>>(menc);
  k_gat_max<<<nb((ll)NEF * 8), 256, 0, stream>>>(src, dst, a_s, a_d, menc);
  hipMemsetAsync(denom, 0, (size_t)NN * 8 * sizeof(float), stream);
  k_gat_exp<<<nb((ll)NEF * 8), 256, 0, stream>>>(src, dst, a_s, a_d, menc, ee, denom);
  k_gat_csr<<<dim3(NN), 256, 0, stream>>>(rowptr, eidb, src, ee, denom,
                                          (const ushort4*)hg, b_g, (ushort4*)gat);

  // ---- GCN1 ----
  gemm_mfma<true><<<dim3(1, MB), 256, 0, stream>>>(gat, Btc1, nullptr, hw64, NN, 64, 1024);
  k_gcn_csr<64, false><<<nb((ll)NN * 64), 256, 0, stream>>>(rowptr, eidb, src, dinv, hw64, b_c1, acc64);

  // ---- GCN2 + log_softmax ----
  gemm_mfma<true><<<dim3(1, MB), 256, 0, stream>>>(acc64, Btc2, nullptr, hw32, NN, 32, 64);
  k_gcn_csr<32, true><<<nb((ll)NN * 32), 256, 0, stream>>>(rowptr, eidb, src, dinv, hw32, b_c2, acc32);
  k_logsoftmax<<<nb(NN), 256, 0, stream>>>(acc32, out);
}

// Round 5
// 315.548 us; speedup vs baseline: 4.2072x; 1.3913x over previous
//
#include <hip/hip_runtime.h>

#define NN 20000
#define NE 160000
#define NEF 180000          // edges + self loops
#define NB1 ((NN + 255) / 256)   // 79 scan blocks

typedef long long ll;
typedef __attribute__((ext_vector_type(4))) float f32x4;
typedef __attribute__((ext_vector_type(8))) short s16x8;

// ---------- bf16 helpers (round-to-nearest-even) ----------
static __device__ __forceinline__ float b2f(ushort u) {
  return __uint_as_float(((unsigned)u) << 16);
}
static __device__ __forceinline__ ushort f2b(float f) {
  unsigned u = __float_as_uint(f);
  return (ushort)((u + 0x7fffu + ((u >> 16) & 1u)) >> 16);
}

// ---------- bf16 MFMA GEMM: C[M,N] = A[M,K] @ Bt[N,K]^T (+bias) ----------
// 4 waves in 2x2; wave = 32x32 via 2x2 16x16x32 frags; no LDS.
// SCORES: emit a_s/a_d partials; each 32-col wave tile owns slot=(bn>>5)&3
// (4 slots per 128-col head -> one writer per slot, race-free).
template<bool SCORES>
__global__ __launch_bounds__(256) void gemm_mfma(
    const ushort* __restrict__ A, const ushort* __restrict__ Bt,
    const float* __restrict__ bias, ushort* __restrict__ C,
    int M, int N, int K,
    const float* __restrict__ att_s, const float* __restrict__ att_d,
    float* __restrict__ a_s4, float* __restrict__ a_d4)
{
  const int wid  = threadIdx.x >> 6;
  const int lane = threadIdx.x & 63;
  const int wr = wid >> 1, wc = wid & 1;
  const int bm = blockIdx.y * 64 + wr * 32;
  const int bn = blockIdx.x * 64 + wc * 32;
  const int lr = lane & 15;
  const int ko = (lane >> 4) * 8;

  int r0 = min(bm + lr,      M - 1);
  int r1 = min(bm + 16 + lr, M - 1);
  int c0 = min(bn + lr,      N - 1);
  int c1 = min(bn + 16 + lr, N - 1);
  const ushort* pa0 = A  + (ll)r0 * K + ko;
  const ushort* pa1 = A  + (ll)r1 * K + ko;
  const ushort* pb0 = Bt + (ll)c0 * K + ko;
  const ushort* pb1 = Bt + (ll)c1 * K + ko;

  f32x4 acc00 = {0.f,0.f,0.f,0.f}, acc01 = acc00, acc10 = acc00, acc11 = acc00;

  #pragma unroll 4
  for (int k = 0; k < K; k += 32) {
    s16x8 a0 = *(const s16x8*)(pa0 + k);
    s16x8 a1 = *(const s16x8*)(pa1 + k);
    s16x8 b0 = *(const s16x8*)(pb0 + k);
    s16x8 b1 = *(const s16x8*)(pb1 + k);
    acc00 = __builtin_amdgcn_mfma_f32_16x16x32_bf16(a0, b0, acc00, 0, 0, 0);
    acc01 = __builtin_amdgcn_mfma_f32_16x16x32_bf16(a0, b1, acc01, 0, 0, 0);
    acc10 = __builtin_amdgcn_mfma_f32_16x16x32_bf16(a1, b0, acc10, 0, 0, 0);
    acc11 = __builtin_amdgcn_mfma_f32_16x16x32_bf16(a1, b1, acc11, 0, 0, 0);
  }

  const int rq = (lane >> 4) * 4;

  if (SCORES) {      // partial a_s/a_d over this wave's 32 cols; head = bn>>7
    int h = bn >> 7;
    int slot = (bn >> 5) & 3;
    float as0 = att_s[bn + lr], as1 = att_s[bn + 16 + lr];
    float ad0 = att_d[bn + lr], ad1 = att_d[bn + 16 + lr];
    #pragma unroll
    for (int i = 0; i < 2; i++) {
      f32x4 aL = i ? acc10 : acc00;
      f32x4 aR = i ? acc11 : acc01;
      #pragma unroll
      for (int r = 0; r < 4; r++) {
        float ss = aL[r] * as0 + aR[r] * as1;
        float dd = aL[r] * ad0 + aR[r] * ad1;
        #pragma unroll
        for (int o = 1; o < 16; o <<= 1) {
          ss += __shfl_xor(ss, o);
          dd += __shfl_xor(dd, o);
        }
        int row = bm + i * 16 + rq + r;
        if (lr == 0 && row < M) {
          a_s4[((ll)slot * NN + row) * 8 + h] = ss;
          a_d4[((ll)slot * NN + row) * 8 + h] = dd;
        }
      }
    }
  }

  #pragma unroll
  for (int i = 0; i < 2; i++) {
    #pragma unroll
    for (int j = 0; j < 2; j++) {
      f32x4 a = (i == 0) ? (j == 0 ? acc00 : acc01) : (j == 0 ? acc10 : acc11);
      int col = bn + j * 16 + lr;
      if (col >= N) continue;
      float bv = bias ? bias[col] : 0.f;
      int rbase = bm + i * 16 + rq;
      #pragma unroll
      for (int r = 0; r < 4; r++) {
        int row = rbase + r;
        if (row >= M) continue;
        C[(ll)row * N + col] = f2b(a[r] + bv);
      }
    }
  }
}

// ---------- sum 4 score slots -> compact a_s/a_d ----------
__global__ void k_score_sum(const float* __restrict__ a_s4, const float* __restrict__ a_d4,
                            float* __restrict__ a_s, float* __restrict__ a_d) {
  int t = blockIdx.x * 256 + threadIdx.x;
  if (t >= NN * 8) return;
  const ll S = (ll)NN * 8;
  a_s[t] = a_s4[t] + a_s4[S + t] + a_s4[2 * S + t] + a_s4[3 * S + t];
  a_d[t] = a_d4[t] + a_d4[S + t] + a_d4[2 * S + t] + a_d4[3 * S + t];
}

// ---------- fused setup: cast x -> bf16, weights -> bf16 transposed, bias packs ----
struct PrepEnt { const float* W; ushort* Bt; int N; int K; int base; };
struct Prep { PrepEnt e[8]; int total; };

__global__ void k_setup(const float* __restrict__ x, ushort* __restrict__ xb, Prep p,
                        const float* __restrict__ b_res, const float* __restrict__ b_l1,
                        const float* __restrict__ b_l2, float* __restrict__ bias192,
                        float* __restrict__ bias256) {
  ll t = (ll)blockIdx.x * 256 + threadIdx.x;
  const ll T0 = (ll)NN * 64;          // each casts 4 floats
  if (t < T0) {
    ll i = t * 4;
    float4 v = *(const float4*)(x + i);
    ushort4 o;
    o.x = f2b(v.x); o.y = f2b(v.y); o.z = f2b(v.z); o.w = f2b(v.w);
    *(ushort4*)(xb + i) = o;
    return;
  }
  t -= T0;
  if (t < p.total) {
    int tt = (int)t;
    #pragma unroll
    for (int i = 0; i < 8; i++) {
      int sz = p.e[i].N * p.e[i].K;
      if (tt >= p.e[i].base && tt < p.e[i].base + sz) {
        int loc = tt - p.e[i].base;
        int n = loc / p.e[i].K, k = loc - n * p.e[i].K;
        p.e[i].Bt[loc] = f2b(p.e[i].W[(ll)k * p.e[i].N + n]);
      }
    }
    return;
  }
  t -= p.total;
  if (t < 256) {
    int tt = (int)t;
    if (tt < 64) bias192[tt] = b_res[tt];
    else if (tt < 128) bias192[tt] = 0.f;
    else if (tt < 192) bias192[tt] = b_l1[tt - 128];
    bias256[tt] = (tt < 128) ? 0.f : b_l2[tt - 128];
  }
}

// ---------- CSR build ----------
__global__ void k_counti(const int* __restrict__ dst, int* __restrict__ icnt) {
  int e = blockIdx.x * 256 + threadIdx.x;
  if (e < NE) atomicAdd(&icnt[dst[e]], 1);
}

__global__ __launch_bounds__(256) void k_scan1(const int* __restrict__ icnt,
                                               int* __restrict__ rowptr,
                                               int* __restrict__ bsum) {
  __shared__ int sd[256];
  int t = threadIdx.x;
  int i = blockIdx.x * 256 + t;
  int v = (i < NN) ? icnt[i] + 1 : 0;   // +1 self loop
  sd[t] = v;
  __syncthreads();
  #pragma unroll
  for (int o = 1; o < 256; o <<= 1) {
    int u = (t >= o) ? sd[t - o] : 0;
    __syncthreads();
    sd[t] += u;
    __syncthreads();
  }
  if (i < NN) rowptr[i] = sd[t] - v;    // block-local exclusive
  if (t == 255) bsum[blockIdx.x] = sd[255];
}

__global__ __launch_bounds__(128) void k_scan2(const int* __restrict__ bsum,
                                               int* __restrict__ boff) {
  __shared__ int sd[128];
  int t = threadIdx.x;
  int v = (t < NB1) ? bsum[t] : 0;
  sd[t] = v;
  __syncthreads();
  #pragma unroll
  for (int o = 1; o < 128; o <<= 1) {
    int u = (t >= o) ? sd[t - o] : 0;
    __syncthreads();
    sd[t] += u;
    __syncthreads();
  }
  if (t < NB1) boff[t] = sd[t] - v;
}

__global__ void k_scan3(int* __restrict__ rowptr, const int* __restrict__ boff,
                        int* __restrict__ cur, const int* __restrict__ icnt,
                        float* __restrict__ dinv) {
  int i = blockIdx.x * 256 + threadIdx.x;
  if (i >= NN) return;
  int r = rowptr[i] + boff[i >> 8];
  rowptr[i] = r;
  cur[i] = r;
  dinv[i] = rsqrtf((float)icnt[i] + 1.0f);
  if (i == 0) rowptr[NN] = NEF;
}

__global__ void k_scatter(const int* __restrict__ dst, int* __restrict__ cur,
                          int* __restrict__ eid) {
  int t = blockIdx.x * 256 + threadIdx.x;
  if (t >= NEF) return;
  int d = (t < NE) ? dst[t] : t - NE;
  int p = atomicAdd(&cur[d], 1);
  eid[p] = t;
}

// ---------- SAGE aggregation: shuffle-staged gather + mean + lin_r + relu (+res) --
template<int C, int STRIDE, bool ADD_RES>
__global__ __launch_bounds__(256) void k_sage_csr(
    const int* __restrict__ rowptr, const int* __restrict__ eid,
    const int* __restrict__ src, const ushort* __restrict__ feat,
    const ushort* __restrict__ linr, const ushort* __restrict__ resx,
    ushort* __restrict__ out)
{
  int node = blockIdx.x * 4 + (threadIdx.x >> 6);
  int lane = threadIdx.x & 63;
  if (node >= NN) return;
  int b = rowptr[node], e = rowptr[node + 1];
  float a0 = 0.f, a1 = 0.f;
  int n = 0;
  for (int base = b; base < e; base += 64) {
    int m = min(64, e - base);
    int sreg = -1;
    if (lane < m) {
      int ed = eid[base + lane];
      sreg = (ed < NE) ? src[ed] : -1;   // self loop excluded from SAGE mean
    }
    for (int i = 0; i < m; i++) {
      int s = __shfl(sreg, i);
      if (s >= 0) {
        a0 += b2f(feat[(ll)s * STRIDE + lane]);
        if (C == 128) a1 += b2f(feat[(ll)s * STRIDE + lane + 64]);
        n++;
      }
    }
  }
  float inv = 1.f / fmaxf((float)n, 1.f);
  {
    float v = a0 * inv + b2f(linr[(ll)node * STRIDE + lane]);
    v = fmaxf(v, 0.f);
    if (ADD_RES) v += b2f(resx[(ll)node * STRIDE + lane]);
    out[(ll)node * C + lane] = f2b(v);
  }
  if (C == 128) {
    float v = a1 * inv + b2f(linr[(ll)node * STRIDE + lane + 64]);
    v = fmaxf(v, 0.f);
    out[(ll)node * C + lane + 64] = f2b(v);
  }
}

// ---------- GAT softmax: thread = (node, head); CSR 2-pass, no atomics ----------
__global__ void k_gat_softmax(const int* __restrict__ rowptr, const int* __restrict__ eid,
                              const int* __restrict__ src, const float* __restrict__ a_s,
                              const float* __restrict__ a_d, float* __restrict__ alpha,
                              float* __restrict__ invden) {
  int t = blockIdx.x * 256 + threadIdx.x;
  if (t >= NN * 8) return;
  int node = t >> 3, h = t & 7;
  int b = rowptr[node], e = rowptr[node + 1];
  float ad = a_d[(ll)node * 8 + h];
  float mx = -3.0e38f;
  for (int p = b; p < e; p++) {
    int ed = eid[p];
    int s = (ed < NE) ? src[ed] : node;
    float v = a_s[(ll)s * 8 + h] + ad;
    v = (v > 0.f) ? v : 0.2f * v;
    mx = fmaxf(mx, v);
  }
  float sum = 0.f;
  for (int p = b; p < e; p++) {
    int ed = eid[p];
    int s = (ed < NE) ? src[ed] : node;
    float v = a_s[(ll)s * 8 + h] + ad;
    v = (v > 0.f) ? v : 0.2f * v;
    float ex = expf(v - mx);
    alpha[(ll)p * 8 + h] = ex;
    sum += ex;
  }
  invden[t] = 1.f / sum;
}

// ---------- GAT aggregation: shuffle-staged, CSR-sequential alpha ----------
__global__ __launch_bounds__(256) void k_gat_csr(
    const int* __restrict__ rowptr, const int* __restrict__ eid,
    const int* __restrict__ src, const float* __restrict__ alpha,
    const float* __restrict__ invden, const ushort4* __restrict__ hg4,
    const float* __restrict__ b_g, ushort4* __restrict__ gat4)
{
  int node = blockIdx.x;
  int t = threadIdx.x;          // 4 channels/thread; 256*4 = 1024
  int h = t >> 5;
  int lane = t & 63;
  float inv = invden[node * 8 + h];
  float ax = 0.f, ay = 0.f, az = 0.f, aw = 0.f;
  int b = rowptr[node], e = rowptr[node + 1];
  for (int base = b; base < e; base += 64) {
    int m = min(64, e - base);
    int sreg = 0;
    if (lane < m) {
      int ed = eid[base + lane];
      sreg = (ed < NE) ? src[ed] : node;
    }
    for (int i = 0; i < m; i++) {
      int s = __shfl(sreg, i);
      float a = alpha[(ll)(base + i) * 8 + h];
      ushort4 v = hg4[(ll)s * 256 + t];
      ax = fmaf(a, b2f(v.x), ax);
      ay = fmaf(a, b2f(v.y), ay);
      az = fmaf(a, b2f(v.z), az);
      aw = fmaf(a, b2f(v.w), aw);
    }
  }
  float4 bb = ((const float4*)b_g)[t];
  ushort4 o;
  o.x = f2b(fmaxf(fmaf(ax, inv, bb.x), 0.f));
  o.y = f2b(fmaxf(fmaf(ay, inv, bb.y), 0.f));
  o.z = f2b(fmaxf(fmaf(az, inv, bb.z), 0.f));
  o.w = f2b(fmaxf(fmaf(aw, inv, bb.w), 0.f));
  gat4[(ll)node * 256 + t] = o;
}

// ---------- GCN aggregation (shuffle-staged src+dinv); optional fused log_softmax --
template<int C, bool FUSE_LSM>
__global__ __launch_bounds__(256) void k_gcn_csr(
    const int* __restrict__ rowptr, const int* __restrict__ eid,
    const int* __restrict__ src, const float* __restrict__ dinv,
    const ushort* __restrict__ hw, const float* __restrict__ bias,
    void* __restrict__ outv)
{
  const int npb = 256 / C;
  int node = blockIdx.x * npb + threadIdx.x / C;
  int c = threadIdx.x & (C - 1);
  if (node >= NN) return;
  int b = rowptr[node], e = rowptr[node + 1];
  float acc = 0.f;
  for (int base = b; base < e; base += C) {
    int m = min(C, e - base);
    int sreg = 0;
    float dreg = 0.f;
    if (c < m) {
      int ed = eid[base + c];
      sreg = (ed < NE) ? src[ed] : node;
      dreg = dinv[sreg];
    }
    for (int i = 0; i < m; i++) {
      int s  = __shfl(sreg, i, C);
      float dv = __shfl(dreg, i, C);
      acc = fmaf(dv, b2f(hw[(ll)s * C + c]), acc);
    }
  }
  float v = acc * dinv[node] + bias[c];
  if (!FUSE_LSM) {
    ((ushort*)outv)[(ll)node * C + c] = f2b(v);
  } else {
    float mx = v;
    #pragma unroll
    for (int o = 16; o > 0; o >>= 1) mx = fmaxf(mx, __shfl_xor(mx, o, 32));
    float s = expf(v - mx);
    #pragma unroll
    for (int o = 16; o > 0; o >>= 1) s += __shfl_xor(s, o, 32);
    ((float*)outv)[(ll)node * C + c] = v - mx - logf(s);
  }
}

extern "C" void kernel_launch(void* const* d_in, const int* in_sizes, int n_in,
                              void* d_out, int out_size, void* d_ws, size_t ws_size,
                              hipStream_t stream) {
  const float* x     = (const float*)d_in[0];
  const int*   ei    = (const int*)d_in[1];
  const float* W_l1  = (const float*)d_in[2];
  const float* b_l1  = (const float*)d_in[3];
  const float* W_r1  = (const float*)d_in[4];
  const float* W_l2  = (const float*)d_in[5];
  const float* b_l2  = (const float*)d_in[6];
  const float* W_r2  = (const float*)d_in[7];
  const float* W_g   = (const float*)d_in[8];
  const float* att_s = (const float*)d_in[9];
  const float* att_d = (const float*)d_in[10];
  const float* b_g   = (const float*)d_in[11];
  const float* W_c1  = (const float*)d_in[12];
  const float* b_c1  = (const float*)d_in[13];
  const float* W_c2  = (const float*)d_in[14];
  const float* b_c2  = (const float*)d_in[15];
  const float* W_res = (const float*)d_in[16];
  const float* b_res = (const float*)d_in[17];
  const int* src = ei;
  const int* dst = ei + NE;
  float* out = (float*)d_out;

  // ---- workspace layout (4-byte units) ----
  float* Wf = (float*)d_ws;
  size_t off = 0;
  auto take = [&](size_t n) { float* p = Wf + off; off += (n + 3) & ~(size_t)3; return p; };
  ushort* xb    = (ushort*)take((size_t)NN * 128);   // x bf16 [NN,256]
  ushort* C192  = (ushort*)take((size_t)NN * 96);    // [resx|xw1|xr1]
  ushort* h1    = (ushort*)take((size_t)NN * 32);    // [NN,64]
  ushort* C256  = (ushort*)take((size_t)NN * 128);   // [hw2|hr2]
  ushort* h2    = (ushort*)take((size_t)NN * 64);    // [NN,128]
  ushort* hg    = (ushort*)take((size_t)NN * 512);   // [NN,1024]
  ushort* gat   = (ushort*)take((size_t)NN * 512);   // [NN,1024]
  ushort* hw64  = (ushort*)take((size_t)NN * 32);
  ushort* acc64 = (ushort*)take((size_t)NN * 32);
  ushort* hw32  = (ushort*)take((size_t)NN * 16);
  ushort* Bt192 = (ushort*)take(192 * 256 / 2);
  ushort* Bt256 = (ushort*)take(256 * 64 / 2);
  ushort* BtG   = (ushort*)take(1024 * 128 / 2);
  ushort* Btc1  = (ushort*)take(64 * 1024 / 2);
  ushort* Btc2  = (ushort*)take(32 * 64 / 2);
  float* bias192 = take(192);
  float* bias256 = take(256);
  int*   icnt   = (int*)take(NN);
  int*   rowptr = (int*)take(NN + 1);
  int*   cur    = (int*)take(NN);
  int*   eidb   = (int*)take(NEF);
  int*   bsum   = (int*)take(NB1);
  int*   boff   = (int*)take(NB1);
  float* dinv   = take(NN);
  float* a_s4   = take((size_t)4 * NN * 8);
  float* a_d4   = take((size_t)4 * NN * 8);
  float* a_s    = take((size_t)NN * 8);
  float* a_d    = take((size_t)NN * 8);
  float* alpha  = take((size_t)NEF * 8);
  float* invden = take((size_t)NN * 8);
  (void)ws_size; (void)in_sizes; (void)n_in; (void)out_size;

  auto nb = [](ll t) { return dim3((unsigned)((t + 255) / 256)); };
  const unsigned MB = (NN + 63) / 64;   // 313

  // ---- CSR build ----
  hipMemsetAsync(icnt, 0, NN * sizeof(int), stream);
  k_counti<<<nb(NE), 256, 0, stream>>>(dst, icnt);
  k_scan1<<<NB1, 256, 0, stream>>>(icnt, rowptr, bsum);
  k_scan2<<<1, 128, 0, stream>>>(bsum, boff);
  k_scan3<<<nb(NN), 256, 0, stream>>>(rowptr, boff, cur, icnt, dinv);
  k_scatter<<<nb(NEF), 256, 0, stream>>>(dst, cur, eidb);

  // ---- setup: cast x, weights -> bf16 transposed, bias packs (one kernel) ----
  Prep pp;
  int base = 0;
  auto ent = [&](int i, const float* W, ushort* Bt, int N_, int K_) {
    pp.e[i] = {W, Bt, N_, K_, base}; base += N_ * K_;
  };
  ent(0, W_res, Bt192,             64, 256);
  ent(1, W_l1,  Bt192 + 64 * 256,  64, 256);
  ent(2, W_r1,  Bt192 + 128 * 256, 64, 256);
  ent(3, W_l2,  Bt256,             128, 64);
  ent(4, W_r2,  Bt256 + 128 * 64,  128, 64);
  ent(5, W_g,   BtG,               1024, 128);
  ent(6, W_c1,  Btc1,              64, 1024);
  ent(7, W_c2,  Btc2,              32, 64);
  pp.total = base;
  k_setup<<<nb((ll)NN * 64 + base + 256), 256, 0, stream>>>(
      x, xb, pp, b_res, b_l1, b_l2, bias192, bias256);

  // ---- SAGE1 (+residual): N=192 GEMM [resx|xw1|xr1] ----
  gemm_mfma<false><<<dim3(3, MB), 256, 0, stream>>>(
      xb, Bt192, bias192, C192, NN, 192, 256, nullptr, nullptr, nullptr, nullptr);
  k_sage_csr<64, 192, true><<<nb((ll)NN * 64), 256, 0, stream>>>(
      rowptr, eidb, src, C192 + 64, C192 + 128, C192, h1);

  // ---- SAGE2: N=256 GEMM [hw2|hr2] ----
  gemm_mfma<false><<<dim3(4, MB), 256, 0, stream>>>(
      h1, Bt256, bias256, C256, NN, 256, 64, nullptr, nullptr, nullptr, nullptr);
  k_sage_csr<128, 256, false><<<nb((ll)NN * 64), 256, 0, stream>>>(
      rowptr, eidb, src, C256, C256 + 128, nullptr, h2);

  // ---- GAT: GEMM with fused a_s/a_d epilogue (4 slots), then sum ----
  gemm_mfma<true><<<dim3(16, MB), 256, 0, stream>>>(
      h2, BtG, nullptr, hg, NN, 1024, 128, att_s, att_d, a_s4, a_d4);
  k_score_sum<<<nb((ll)NN * 8), 256, 0, stream>>>(a_s4, a_d4, a_s, a_d);
  k_gat_softmax<<<nb((ll)NN * 8), 256, 0, stream>>>(
      rowptr, eidb, src, a_s, a_d, alpha, invden);
  k_gat_csr<<<dim3(NN), 256, 0, stream>>>(
      rowptr, eidb, src, alpha, invden, (const ushort4*)hg, b_g, (ushort4*)gat);

  // ---- GCN1 ----
  gemm_mfma<false><<<dim3(1, MB), 256, 0, stream>>>(
      gat, Btc1, nullptr, hw64, NN, 64, 1024, nullptr, nullptr, nullptr, nullptr);
  k_gcn_csr<64, false><<<nb((ll)NN * 64), 256, 0, stream>>>(
      rowptr, eidb, src, dinv, hw64, b_c1, acc64);

  // ---- GCN2 + fused log_softmax ----
  gemm_mfma<false><<<dim3(1, MB), 256, 0, stream>>>(
      acc64, Btc2, nullptr, hw32, NN, 32, 64, nullptr, nullptr, nullptr, nullptr);
  k_gcn_csr<32, true><<<nb((ll)NN * 32), 256, 0, stream>>>(
      rowptr, eidb, src, dinv, hw32, b_c2, out);
}